// Round 14
// baseline (59.665 us; speedup 1.0000x reference)
//
#include <hip/hip_runtime.h>
#include <stdint.h>

typedef __bf16 bf16;
typedef __attribute__((ext_vector_type(8))) __bf16 bfx8;
typedef __attribute__((ext_vector_type(4))) float f32x4;

__device__ inline f32x4 mfma16(bfx8 a, bfx8 b, f32x4 c) {
  return __builtin_amdgcn_mfma_f32_16x16x32_bf16(a, b, c, 0, 0, 0);
}

// Async 16B global->LDS (chunk_out Q/K staging).
__device__ inline void gl16(const bf16* g, bf16* lbase, int lane) {
#if __has_builtin(__builtin_amdgcn_global_load_lds)
  (void)lane;
  __builtin_amdgcn_global_load_lds(
      (const __attribute__((address_space(1))) void*)g,
      (__attribute__((address_space(3))) void*)lbase, 16, 0, 0);
#else
  *(bfx8*)(lbase + lane * 8) = *(const bfx8*)g;
#endif
}

// Image convention: 64x64 bf16 tile stored as 4096 elems, 16B chunks
// XOR-swizzled per row: element (i,e) lives at i*64 + (((e>>3)^(i&7))<<3) + (e&7).
__device__ inline int img_off(int i, int e) {
  return i * 64 + ((((e >> 3) ^ (i & 7)) << 3)) + (e & 7);
}

__device__ inline bfx8 cvt8(const float* s) {
  f32x4 x0 = *(const f32x4*)s, x1 = *(const f32x4*)(s + 4);
  bfx8 v;
  v[0] = (bf16)x0[0]; v[1] = (bf16)x0[1]; v[2] = (bf16)x0[2]; v[3] = (bf16)x0[3];
  v[4] = (bf16)x1[0]; v[5] = (bf16)x1[1]; v[6] = (bf16)x1[2]; v[7] = (bf16)x1[3];
  return v;
}

// ---------------- projection GEMMs: z in {Q,K,V}, in-kernel weight cvt ----------------
// Tile 64x128, BK=64, 4 waves (2x2), acc[2][4]. 768 equal blocks.
struct P3Args {
  const float *Q, *K, *V, *Wq, *Wk, *Wv;
  bf16 *Qimg, *Kimg, *Vimg;
};

__global__ __launch_bounds__(256) void proj3(P3Args pa) {
  const int z = blockIdx.z;
  const float* Ag = (z == 0) ? pa.Q : (z == 1) ? pa.K : pa.V;
  const float* Wg = (z == 0) ? pa.Wq : (z == 1) ? pa.Wk : pa.Wv;
  bf16* ob = (z == 0) ? pa.Qimg : (z == 1) ? pa.Kimg : pa.Vimg;
  const bool phi = z < 2;
  const int tm = blockIdx.x * 64, tn = blockIdx.y * 128;
  const int tid = threadIdx.x, l = tid & 63, w = tid >> 6;
  const int wm = w >> 1, wn = w & 1, lm = l & 15, lk = l >> 4;

  __shared__ __align__(16) bf16 As[64 * 64];
  __shared__ __align__(16) bf16 Bs[128 * 64];
  f32x4 acc[2][4] = {};

  for (int kt = 0; kt < 8; ++kt) {
#pragma unroll
    for (int it = 0; it < 4; ++it) {
      int c = it * 256 + tid, row = c >> 3, t8 = c & 7;
      bfx8 v = cvt8(Wg + (size_t)(tn + row) * 512 + kt * 64 + t8 * 8);
      *(bfx8*)&Bs[row * 64 + ((t8 ^ (row & 7)) << 3)] = v;
    }
#pragma unroll
    for (int it = 0; it < 2; ++it) {
      int c = it * 256 + tid, row = c >> 3, t8 = c & 7;
      bfx8 v = cvt8(Ag + (size_t)(tm + row) * 512 + kt * 64 + t8 * 8);
      *(bfx8*)&As[row * 64 + ((t8 ^ (row & 7)) << 3)] = v;
    }
    __syncthreads();
#pragma unroll
    for (int ks = 0; ks < 2; ++ks) {
      bfx8 af[2], bfr[4];
#pragma unroll
      for (int i = 0; i < 2; ++i) {
        int ra = wm * 32 + i * 16 + lm;
        af[i] = *(const bfx8*)&As[ra * 64 + (((ks * 4 + lk) ^ (ra & 7)) << 3)];
      }
#pragma unroll
      for (int j = 0; j < 4; ++j) {
        int rb = wn * 64 + j * 16 + lm;
        bfr[j] = *(const bfx8*)&Bs[rb * 64 + (((ks * 4 + lk) ^ (rb & 7)) << 3)];
      }
#pragma unroll
      for (int i = 0; i < 2; ++i)
#pragma unroll
        for (int j = 0; j < 4; ++j)
          acc[i][j] = mfma16(af[i], bfr[j], acc[i][j]);
    }
    __syncthreads();
  }

#pragma unroll
  for (int i = 0; i < 2; ++i)
#pragma unroll
    for (int j = 0; j < 4; ++j)
#pragma unroll
      for (int r = 0; r < 4; ++r) {
        int m = tm + wm * 32 + i * 16 + lk * 4 + r;
        int n = tn + wn * 64 + j * 16 + lm;
        float v = acc[i][j][r];
        if (phi) v = v > 0.f ? v + 1.f : __expf(v);
        ob[((size_t)((m >> 6) * 8 + (n >> 6)) << 12) + img_off(m & 63, n & 63)] =
            (bf16)v;
      }
}

// ---------------- attention stage 1: per-chunk KV^T (bf16) + ksum ----------------
__global__ __launch_bounds__(256) void chunk_kv(const bf16* __restrict__ Kimg,
                                                const bf16* __restrict__ Vimg,
                                                bf16* __restrict__ KVb,
                                                float* __restrict__ ksums) {
  const int bh = blockIdx.x, c = blockIdx.y, b = bh >> 3, h = bh & 7;
  const int tid = threadIdx.x, l = tid & 63, w = tid >> 6, lm = l & 15, lk = l >> 4;
  __shared__ __align__(16) bf16 KTs[64 * 64];
  __shared__ __align__(16) bf16 VTs[64 * 64];
  __shared__ float ksum_p[256];

  const size_t tb = (size_t)((b * 16 + c) * 8 + h) << 12;
  const bf16* Kt = Kimg + tb;
  const bf16* Vt = Vimg + tb;
  const int sr = tid >> 2, sp = tid & 3;
  {
    bfx8 k0 = *(const bfx8*)&Kt[sr * 64 + (((2 * sp) ^ (sr & 7)) << 3)];
    bfx8 k1 = *(const bfx8*)&Kt[sr * 64 + (((2 * sp + 1) ^ (sr & 7)) << 3)];
    bfx8 v0 = *(const bfx8*)&Vt[sr * 64 + (((2 * sp) ^ (sr & 7)) << 3)];
    bfx8 v1 = *(const bfx8*)&Vt[sr * 64 + (((2 * sp + 1) ^ (sr & 7)) << 3)];
#pragma unroll
    for (int q = 0; q < 8; ++q) {
      int d0 = sp * 16 + q, d1 = sp * 16 + 8 + q;
      KTs[d0 * 64 + (((sr >> 3) ^ (d0 & 7)) << 3) + (sr & 7)] = k0[q];
      KTs[d1 * 64 + (((sr >> 3) ^ (d1 & 7)) << 3) + (sr & 7)] = k1[q];
      VTs[d0 * 64 + (((sr >> 3) ^ (d0 & 7)) << 3) + (sr & 7)] = v0[q];
      VTs[d1 * 64 + (((sr >> 3) ^ (d1 & 7)) << 3) + (sr & 7)] = v1[q];
    }
  }
  __syncthreads();
  {
    int d = tid & 63, jp = tid >> 6;
    float s = 0.f;
#pragma unroll
    for (int q = 0; q < 16; ++q) {
      int j = jp * 16 + q;
      s += (float)KTs[d * 64 + (((j >> 3) ^ (d & 7)) << 3) + (j & 7)];
    }
    ksum_p[jp * 64 + d] = s;
  }
  f32x4 kacc[4] = {};
#pragma unroll
  for (int ks = 0; ks < 2; ++ks) {
    int r = w * 16 + lm;
    bfx8 av = *(const bfx8*)&VTs[r * 64 + (((ks * 4 + lk) ^ (r & 7)) << 3)];
#pragma unroll
    for (int bn = 0; bn < 4; ++bn) {
      int e = bn * 16 + lm;
      bfx8 bk = *(const bfx8*)&KTs[e * 64 + (((ks * 4 + lk) ^ (e & 7)) << 3)];
      kacc[bn] = mfma16(av, bk, kacc[bn]);
    }
  }
  bf16* st = KVb + (size_t)(bh * 16 + c) * 4096;
#pragma unroll
  for (int bn = 0; bn < 4; ++bn)
#pragma unroll
    for (int rg = 0; rg < 4; ++rg) {
      int e = w * 16 + lk * 4 + rg, d = bn * 16 + lm;
      st[e * 64 + d] = (bf16)kacc[bn][rg];
    }
  __syncthreads();
  if (tid < 64)
    ksums[(size_t)(bh * 16 + c) * 64 + tid] =
        ksum_p[tid] + ksum_p[64 + tid] + ksum_p[128 + tid] + ksum_p[192 + tid];
}

// ---------------- attention stage 2: per-chunk output (heavy chunks first) ----------------
__global__ __launch_bounds__(256) void chunk_out(const bf16* __restrict__ Qimg,
                                                 const bf16* __restrict__ Kimg,
                                                 const bf16* __restrict__ Vimg,
                                                 const bf16* __restrict__ KVb,
                                                 const float* __restrict__ ksums,
                                                 bf16* __restrict__ Obsw) {
  const int c = 15 - blockIdx.x, bh = blockIdx.y, b = bh >> 3, h = bh & 7;
  const int tid = threadIdx.x, l = tid & 63, w = tid >> 6, lm = l & 15, lk = l >> 4;

  __shared__ __align__(16) bf16 Qs[64 * 64];
  __shared__ __align__(16) bf16 Ks[64 * 64];
  __shared__ __align__(16) bf16 VTs[64 * 64];
  __shared__ __align__(16) bf16 Ss[64 * 64];
  __shared__ __align__(16) bf16 KVL[64 * 64];
  __shared__ float ksum[64], den_i[64], den_all[64], den_p[256];

  const size_t tb = (size_t)((b * 16 + c) * 8 + h) << 12;
  const int sr = tid >> 2, sp = tid & 3;

#pragma unroll
  for (int q = 0; q < 2; ++q) {
    int cb = (q * 4 + w) * 64;
    gl16(Qimg + tb + (size_t)(cb + l) * 8, &Qs[cb * 8], l);
    gl16(Kimg + tb + (size_t)(cb + l) * 8, &Ks[cb * 8], l);
  }
  {
    const bf16* Vt = Vimg + tb;
    bfx8 v0 = *(const bfx8*)&Vt[sr * 64 + (((2 * sp) ^ (sr & 7)) << 3)];
    bfx8 v1 = *(const bfx8*)&Vt[sr * 64 + (((2 * sp + 1) ^ (sr & 7)) << 3)];
#pragma unroll
    for (int q = 0; q < 8; ++q) {
      int d0 = sp * 16 + q, d1 = sp * 16 + 8 + q;
      VTs[d0 * 64 + (((sr >> 3) ^ (d0 & 7)) << 3) + (sr & 7)] = v0[q];
      VTs[d1 * 64 + (((sr >> 3) ^ (d1 & 7)) << 3) + (sr & 7)] = v1[q];
    }
  }
  {
    const int e = sr, dp = sp * 16;
    float s0[8] = {}, s1[8] = {};
    const bf16* kb = KVb + (size_t)(bh * 16) * 4096 + e * 64 + dp;
    for (int cc = 0; cc < c; ++cc) {
      bfx8 x0 = *(const bfx8*)(kb + (size_t)cc * 4096);
      bfx8 x1 = *(const bfx8*)(kb + (size_t)cc * 4096 + 8);
#pragma unroll
      for (int q = 0; q < 8; ++q) { s0[q] += (float)x0[q]; s1[q] += (float)x1[q]; }
    }
    bfx8 y0, y1;
#pragma unroll
    for (int q = 0; q < 8; ++q) { y0[q] = (bf16)s0[q]; y1[q] = (bf16)s1[q]; }
    *(bfx8*)&KVL[e * 64 + (((2 * sp) ^ (e & 7)) << 3)] = y0;
    *(bfx8*)&KVL[e * 64 + (((2 * sp + 1) ^ (e & 7)) << 3)] = y1;
    if (tid < 64) {
      float s = 0.f;
      const float* kp = ksums + (size_t)(bh * 16) * 64 + tid;
      for (int cc = 0; cc < c; ++cc) s += kp[(size_t)cc * 64];
      ksum[tid] = s;
    }
  }
  __syncthreads();

  f32x4 sacc[4] = {};
  bfx8 aq[2];
#pragma unroll
  for (int ks = 0; ks < 2; ++ks) {
    int r = w * 16 + lm;
    aq[ks] = *(const bfx8*)&Qs[r * 64 + (((ks * 4 + lk) ^ (r & 7)) << 3)];
#pragma unroll
    for (int bn = 0; bn < 4; ++bn) {
      int rb = bn * 16 + lm;
      bfx8 bk = *(const bfx8*)&Ks[rb * 64 + (((ks * 4 + lk) ^ (rb & 7)) << 3)];
      sacc[bn] = mfma16(aq[ks], bk, sacc[bn]);
    }
  }
  float prs[4] = {0.f, 0.f, 0.f, 0.f};
#pragma unroll
  for (int bn = 0; bn < 4; ++bn)
#pragma unroll
    for (int rg = 0; rg < 4; ++rg) {
      int i = w * 16 + lk * 4 + rg, j = bn * 16 + lm;
      float v = (j <= i) ? sacc[bn][rg] : 0.f;
      prs[rg] += v;
      Ss[i * 64 + (((j >> 3) ^ (i & 7)) << 3) + (j & 7)] = (bf16)v;
    }
#pragma unroll
  for (int m = 1; m < 16; m <<= 1) {
#pragma unroll
    for (int rg = 0; rg < 4; ++rg) prs[rg] += __shfl_xor(prs[rg], m, 64);
  }
  if (lm == 0) {
#pragma unroll
    for (int rg = 0; rg < 4; ++rg) den_i[w * 16 + lk * 4 + rg] = prs[rg];
  }
  {
    float s = 0.f;
#pragma unroll
    for (int q = 0; q < 16; ++q) {
      int d = sp * 16 + q;
      s += (float)Qs[sr * 64 + (((d >> 3) ^ (sr & 7)) << 3) + (d & 7)] * ksum[d];
    }
    den_p[sp * 64 + sr] = s;
  }
  __syncthreads();

  if (tid < 64)
    den_all[tid] = den_i[tid] + den_p[tid] + den_p[64 + tid] + den_p[128 + tid] + den_p[192 + tid];
  f32x4 oacc[4] = {};
#pragma unroll
  for (int ks = 0; ks < 2; ++ks) {
    int r = w * 16 + lm;
    bfx8 as_ = *(const bfx8*)&Ss[r * 64 + (((ks * 4 + lk) ^ (r & 7)) << 3)];
#pragma unroll
    for (int bn = 0; bn < 4; ++bn) {
      int e = bn * 16 + lm;
      bfx8 bv = *(const bfx8*)&VTs[e * 64 + (((ks * 4 + lk) ^ (e & 7)) << 3)];
      oacc[bn] = mfma16(as_, bv, oacc[bn]);
      bfx8 bkv = *(const bfx8*)&KVL[e * 64 + (((ks * 4 + lk) ^ (e & 7)) << 3)];
      oacc[bn] = mfma16(aq[ks], bkv, oacc[bn]);
    }
  }
  __syncthreads();

  bf16* ot = Obsw + tb;
#pragma unroll
  for (int bn = 0; bn < 4; ++bn)
#pragma unroll
    for (int rg = 0; rg < 4; ++rg) {
      int i = w * 16 + lk * 4 + rg, e = bn * 16 + lm;
      float o = oacc[bn][rg] / (den_all[i] + 1e-6f);
      ot[img_off(i, e)] = (bf16)o;
    }
}

// ---------------- output GEMM: out = Obsw @ Wo^T (fp32 out, in-kernel W cvt) ----------------
__global__ __launch_bounds__(256) void out_gemm(const bf16* __restrict__ Obsw,
                                                const float* __restrict__ Wo,
                                                float* __restrict__ out) {
  const int bid = blockIdx.x;
  const int tm = (bid >> 2) * 64, tn = (bid & 3) * 128;
  const int tid = threadIdx.x, l = tid & 63, w = tid >> 6;
  const int wm = w >> 1, wn = w & 1, lm = l & 15, lk = l >> 4;

  __shared__ __align__(16) bf16 As[64 * 64];
  __shared__ __align__(16) bf16 Bs[128 * 64];
  f32x4 acc[2][4] = {};

  for (int kt = 0; kt < 8; ++kt) {
#pragma unroll
    for (int it = 0; it < 4; ++it) {
      int c = it * 256 + tid, row = c >> 3, t8 = c & 7;
      bfx8 v = cvt8(Wo + (size_t)(tn + row) * 512 + kt * 64 + t8 * 8);
      *(bfx8*)&Bs[row * 64 + ((t8 ^ (row & 7)) << 3)] = v;
    }
    const bf16* asrc = Obsw + ((size_t)((tm >> 6) * 8 + kt) << 12);
#pragma unroll
    for (int it = 0; it < 2; ++it) {
      int c = it * 256 + tid;
      *(bfx8*)&As[c * 8] = *(const bfx8*)(asrc + (size_t)c * 8);
    }
    __syncthreads();
#pragma unroll
    for (int ks = 0; ks < 2; ++ks) {
      bfx8 af[2], bfr[4];
#pragma unroll
      for (int i = 0; i < 2; ++i) {
        int ra = wm * 32 + i * 16 + lm;
        af[i] = *(const bfx8*)&As[ra * 64 + (((ks * 4 + lk) ^ (ra & 7)) << 3)];
      }
#pragma unroll
      for (int j = 0; j < 4; ++j) {
        int rb = wn * 64 + j * 16 + lm;
        bfr[j] = *(const bfx8*)&Bs[rb * 64 + (((ks * 4 + lk) ^ (rb & 7)) << 3)];
      }
#pragma unroll
      for (int i = 0; i < 2; ++i)
#pragma unroll
        for (int j = 0; j < 4; ++j)
          acc[i][j] = mfma16(af[i], bfr[j], acc[i][j]);
    }
    __syncthreads();
  }
#pragma unroll
  for (int i = 0; i < 2; ++i)
#pragma unroll
    for (int j = 0; j < 4; ++j)
#pragma unroll
      for (int r = 0; r < 4; ++r) {
        int m = tm + wm * 32 + i * 16 + lk * 4 + r;
        int n = tn + wn * 64 + j * 16 + lm;
        out[(size_t)m * 512 + n] = acc[i][j][r];
      }
}

// ---------------- launch ----------------
extern "C" void kernel_launch(void* const* d_in, const int* in_sizes, int n_in,
                              void* d_out, int out_size, void* d_ws, size_t ws_size,
                              hipStream_t stream) {
  (void)in_sizes; (void)n_in; (void)out_size; (void)ws_size;
  char* wsp = (char*)d_ws;
  const size_t MB = 1ull << 20;

  P3Args pa;
  pa.Q = (const float*)d_in[0];
  pa.K = (const float*)d_in[1];
  pa.V = (const float*)d_in[2];
  pa.Wq = (const float*)d_in[3];
  pa.Wk = (const float*)d_in[4];
  pa.Wv = (const float*)d_in[5];
  pa.Qimg = (bf16*)(wsp + 0 * MB);
  pa.Kimg = (bf16*)(wsp + 4 * MB);
  pa.Vimg = (bf16*)(wsp + 8 * MB);
  bf16* Obsw = (bf16*)(wsp + 12 * MB);
  bf16* KVb = (bf16*)(wsp + 16 * MB);
  float* ksums = (float*)(wsp + 20 * MB);

  proj3<<<dim3(64, 4, 3), 256, 0, stream>>>(pa);
  chunk_kv<<<dim3(32, 16), 256, 0, stream>>>(pa.Kimg, pa.Vimg, KVb, ksums);
  chunk_out<<<dim3(16, 32), 256, 0, stream>>>(pa.Qimg, pa.Kimg, pa.Vimg, KVb,
                                              ksums, Obsw);
  out_gemm<<<256, 256, 0, stream>>>(Obsw, (const float*)d_in[6], (float*)d_out);
}